// Round 10
// baseline (661.937 us; speedup 1.0000x reference)
//
#include <hip/hip_runtime.h>

#define BB   128
#define TT   512
#define FF   40
#define WW   10
#define NS   503            // window starts (stride 1): T-W+1
#define NP   780            // F*(F-1)/2
#define SC   64             // steps per block (uniform; last chunk overlaps)
#define NCHUNK 8
#define NT   512            // threads per block (8 waves)
#define EPSC 1e-5f

// 512 threads x 2 pair-slots, FULLY rolling: each thread keeps sx_i,sxx_i,
// sx_j,sxx_j,sxy in registers -- NO stats LDS table, no history arrays.
// Per step per slot: read x_old/x_new for i and j (read2_b32-mergeable pairs
// in the 2-step body), recompute mean/istd on VALU (v_sqrt + v_rcp).
// ~35 VGPR -> (512,8) cap 64 safe; one barrier total; LDS = 11.8 KB.
// Slot1 lanes past the triangle compute DISTINCT duplicate pairs (p-268+244)
// -> distinct addresses, same cache lines, bit-identical values.
__global__ __launch_bounds__(NT, 8) void ts_corr_r10(const float* __restrict__ in,
                                                     float* __restrict__ out) {
    const int blk = blockIdx.x;
    const int b   = blk >> 3;              // / NCHUNK
    const int c   = blk & (NCHUNK - 1);
    const int s0  = (c == NCHUNK - 1) ? (NS - SC) : c * SC;   // 439 tail; overlap rows identical
    const int tid = threadIdx.x;

    __shared__ float xs[SC + WW][FF];   // 74 rows: 73 data + 1 pad (epilogue read shield)

    // ---- stage 73-row slab (730 float4, coalesced) ----
    const float4* src4 = (const float4*)(in + ((size_t)b * TT + s0) * FF);
    float4* xs4 = (float4*)&xs[0][0];
    xs4[tid] = src4[tid];
    {
        const int i2 = tid + NT;
        if (i2 < (SC + WW - 1) * FF / 4) xs4[i2] = src4[i2];
    }
    __syncthreads();   // the only barrier

    // ---- slot setup: pair unrank + initial window sums ----
    int pi[2], pj[2], poff[2];
    float sxy[2], sxi[2], sqi[2], sxj[2], sqj[2];
    #pragma unroll
    for (int k = 0; k < 2; ++k) {
        int p = tid + k * NT;
        if (p >= NP) p = p - NP + 512;     // = tid + 244: distinct dup pairs [512,755]
        poff[k] = p;
        int i = (int)((79.0f - sqrtf((float)(6241 - 8 * p))) * 0.5f);
        while (i > 0 && i * (79 - i) / 2 > p) --i;
        while ((i + 1) * (79 - (i + 1)) / 2 <= p) ++i;
        pi[k] = i;
        pj[k] = p - i * (79 - i) / 2 + i + 1;
        float sx = 0.f, sq = 0.f, tx = 0.f, tq = 0.f, s = 0.f;
        #pragma unroll
        for (int w = 0; w < WW; ++w) {
            const float xi = xs[w][pi[k]], xj = xs[w][pj[k]];
            sx += xi; sq += xi * xi;
            tx += xj; tq += xj * xj;
            s  += xi * xj;
        }
        sxi[k] = sx; sqi[k] = sq; sxj[k] = tx; sqj[k] = tq; sxy[k] = s;
    }

    float* dstB = out + (size_t)(b * NS + s0) * NP;

#define CORR(K) ({                                                              \
    const float _mi = sxi[K] * 0.1f, _mj = sxj[K] * 0.1f;                       \
    const float _vi = fmaxf(sqi[K] * 0.1f - _mi * _mi, 0.f);                    \
    const float _vj = fmaxf(sqj[K] * 0.1f - _mj * _mj, 0.f);                    \
    const float _di = __builtin_amdgcn_sqrtf(_vi) + EPSC;                       \
    const float _dj = __builtin_amdgcn_sqrtf(_vj) + EPSC;                       \
    (sxy[K] * 0.1f - _mi * _mj) * __builtin_amdgcn_rcpf(_di * _dj);             \
})

#define UPD(K, XO_I, XN_I, XO_J, XN_J) do {                                     \
    sxi[K] += (XN_I) - (XO_I);                                                  \
    sqi[K] += (XN_I) * (XN_I) - (XO_I) * (XO_I);                                \
    sxj[K] += (XN_J) - (XO_J);                                                  \
    sqj[K] += (XN_J) * (XN_J) - (XO_J) * (XO_J);                                \
    sxy[K] += (XN_I) * (XN_J) - (XO_I) * (XO_J);                                \
} while (0)

// Two steps (TA, TA+1). Old pair (t, t+1) and new pair (t+10, t+11) are each
// a ds_read2_b32 (delta 40 dwords). Stores fully coalesced dwords.
#define STEP2(TA) do {                                                          \
    float* _dA = dstB + (size_t)(TA) * NP;                                      \
    float* _dB = _dA + NP;                                                      \
    _Pragma("unroll")                                                           \
    for (int k = 0; k < 2; ++k) {                                               \
        const int _ii = pi[k], _jj = pj[k];                                     \
        const float _oiA = xs[(TA)][_ii],          _oiB = xs[(TA) + 1][_ii];    \
        const float _niA = xs[(TA) + WW][_ii],     _niB = xs[(TA) + WW + 1][_ii]; \
        const float _ojA = xs[(TA)][_jj],          _ojB = xs[(TA) + 1][_jj];    \
        const float _njA = xs[(TA) + WW][_jj],     _njB = xs[(TA) + WW + 1][_jj]; \
        _dA[poff[k]] = CORR(k);                                                 \
        UPD(k, _oiA, _niA, _ojA, _njA);                                         \
        _dB[poff[k]] = CORR(k);                                                 \
        UPD(k, _oiB, _niB, _ojB, _njB);  /* t=63: reads pad row 73, dead */     \
    }                                                                           \
} while (0)

    // ---- phase 2: 64 steps, barrier-free, branch-free ----
    for (int t0 = 0; t0 < 60; t0 += 10) {
        STEP2(t0);
        STEP2(t0 + 2);
        STEP2(t0 + 4);
        STEP2(t0 + 6);
        STEP2(t0 + 8);
    }
    STEP2(60);
    STEP2(62);
#undef STEP2
#undef UPD
#undef CORR
}

extern "C" void kernel_launch(void* const* d_in, const int* in_sizes, int n_in,
                              void* d_out, int out_size, void* d_ws, size_t ws_size,
                              hipStream_t stream) {
    const float* in = (const float*)d_in[0];
    float* out = (float*)d_out;
    ts_corr_r10<<<BB * NCHUNK, NT, 0, stream>>>(in, out);
}

// Round 11
// 88.992 us; speedup vs baseline: 7.4382x; 7.4382x over previous
//
#include <hip/hip_runtime.h>

#define BB   128
#define TT   512
#define FF   40
#define WW   10
#define NS   503            // window starts (stride 1): T-W+1
#define NP   780            // F*(F-1)/2
#define SC   64             // steps per block (uniform; last chunk overlaps)
#define NCHUNK 8
#define NT   512            // threads per block (8 waves)

// 512 threads x 2 pair-slots, register-rolling: each thread keeps
// sx_i,sxx_i,sx_j,sxx_j,sxy in registers -- no stats LDS table, no history
// array, one barrier, branch-free phase 2.
// NO min-waves launch-bounds hint: r7/r10 showed it forces spills (hbm 2.8GB);
// natural ~50-70 VGPR -> 16-24 waves/CU, which r6/r8 showed is enough TLP.
// Slot1 lanes past the triangle (tid>=268) recompute pairs [512,755]:
// distinct addresses, bit-identical values (same LDS data, same ops).
__global__ __launch_bounds__(NT) void ts_corr_r11(const float* __restrict__ in,
                                                  float* __restrict__ out) {
    const int blk = blockIdx.x;
    const int b   = blk >> 3;              // / NCHUNK
    const int c   = blk & (NCHUNK - 1);
    const int s0  = (c == NCHUNK - 1) ? (NS - SC) : c * SC;   // 439 tail; overlap rows identical
    const int tid = threadIdx.x;

    __shared__ float xs[SC + WW][FF];   // 74 rows: 73 staged + 1 pad (epilogue read shield)

    // ---- stage 73-row slab (730 float4, coalesced) ----
    const float4* src4 = (const float4*)(in + ((size_t)b * TT + s0) * FF);
    float4* xs4 = (float4*)&xs[0][0];
    xs4[tid] = src4[tid];
    {
        const int i2 = tid + NT;
        if (i2 < (SC + WW - 1) * FF / 4) xs4[i2] = src4[i2];
    }
    __syncthreads();   // the only barrier

    // ---- slot setup: pair unrank + initial window sums ----
    int pi[2], pj[2], poff[2];
    float sxy[2], sxi[2], sqi[2], sxj[2], sqj[2];
    #pragma unroll
    for (int k = 0; k < 2; ++k) {
        int p = tid + k * NT;
        if (p >= NP) p = p - NP + 512;     // = tid + 244: dup pairs [512,755], distinct addrs
        poff[k] = p;
        int i = (int)((79.0f - sqrtf((float)(6241 - 8 * p))) * 0.5f);
        while (i > 0 && i * (79 - i) / 2 > p) --i;
        while ((i + 1) * (79 - (i + 1)) / 2 <= p) ++i;
        pi[k] = i;
        pj[k] = p - i * (79 - i) / 2 + i + 1;
        float sx = 0.f, sq = 0.f, tx = 0.f, tq = 0.f, s = 0.f;
        #pragma unroll
        for (int w = 0; w < WW; ++w) {
            const float xi = xs[w][pi[k]], xj = xs[w][pj[k]];
            sx += xi; sq += xi * xi;
            tx += xj; tq += xj * xj;
            s  += xi * xj;
        }
        sxi[k] = sx; sqi[k] = sq; sxj[k] = tx; sqj[k] = tq; sxy[k] = s;
    }

    float* dstB = out + (size_t)(b * NS + s0) * NP;

// corr = (Sxy/10 - mi*mj) * rsqrt(vi*vj); EPS dropped (rel err ~2e-5 << thr).
#define CORR(K) ({                                                              \
    const float _mi = sxi[K] * 0.1f, _mj = sxj[K] * 0.1f;                       \
    const float _vi = fmaxf(sqi[K] * 0.1f - _mi * _mi, 1e-12f);                 \
    const float _vj = fmaxf(sqj[K] * 0.1f - _mj * _mj, 1e-12f);                 \
    (sxy[K] * 0.1f - _mi * _mj) * rsqrtf(_vi * _vj);                            \
})

#define UPD(K, XO_I, XN_I, XO_J, XN_J) do {                                     \
    sxi[K] += (XN_I) - (XO_I);                                                  \
    sqi[K] += (XN_I) * (XN_I) - (XO_I) * (XO_I);                                \
    sxj[K] += (XN_J) - (XO_J);                                                  \
    sqj[K] += (XN_J) * (XN_J) - (XO_J) * (XO_J);                                \
    sxy[K] += (XN_I) * (XN_J) - (XO_I) * (XO_J);                                \
} while (0)

// Two steps (TA, TA+1). Old pair (t,t+1) and new pair (t+10,t+11) each merge
// into ds_read2_b32 (delta 40 dwords). Stores fully coalesced dwords.
#define STEP2(TA) do {                                                          \
    float* _dA = dstB + (size_t)(TA) * NP;                                      \
    float* _dB = _dA + NP;                                                      \
    _Pragma("unroll")                                                           \
    for (int k = 0; k < 2; ++k) {                                               \
        const int _ii = pi[k], _jj = pj[k];                                     \
        const float _oiA = xs[(TA)][_ii],          _oiB = xs[(TA) + 1][_ii];    \
        const float _niA = xs[(TA) + WW][_ii],     _niB = xs[(TA) + WW + 1][_ii]; \
        const float _ojA = xs[(TA)][_jj],          _ojB = xs[(TA) + 1][_jj];    \
        const float _njA = xs[(TA) + WW][_jj],     _njB = xs[(TA) + WW + 1][_jj]; \
        _dA[poff[k]] = CORR(k);                                                 \
        UPD(k, _oiA, _niA, _ojA, _njA);                                         \
        _dB[poff[k]] = CORR(k);                                                 \
        UPD(k, _oiB, _niB, _ojB, _njB);  /* TA=62: B-update reads pad row 73, dead */ \
    }                                                                           \
} while (0)

    // ---- phase 2: 64 steps, barrier-free, branch-free ----
    for (int t0 = 0; t0 < 60; t0 += 10) {
        STEP2(t0);
        STEP2(t0 + 2);
        STEP2(t0 + 4);
        STEP2(t0 + 6);
        STEP2(t0 + 8);
    }
    STEP2(60);
    STEP2(62);
#undef STEP2
#undef UPD
#undef CORR
}

extern "C" void kernel_launch(void* const* d_in, const int* in_sizes, int n_in,
                              void* d_out, int out_size, void* d_ws, size_t ws_size,
                              hipStream_t stream) {
    const float* in = (const float*)d_in[0];
    float* out = (float*)d_out;
    ts_corr_r11<<<BB * NCHUNK, NT, 0, stream>>>(in, out);
}

// Round 12
// 57.026 us; speedup vs baseline: 11.6077x; 1.5606x over previous
//
#include <hip/hip_runtime.h>

#define BB   128
#define TT   512
#define FF   40
#define WW   10
#define NS   503            // window starts (stride 1): T-W+1
#define NP   780            // F*(F-1)/2
#define SC   64             // steps per block (uniform; last chunk overlaps)
#define NCHUNK 8
#define ROWS (SC + WW - 1)  // 73 staged rows
#define NT   512            // threads per block (8 waves)
#define EPSC 1e-5f
#define C01  0.31622776601683794f   // sqrt(0.1)

// r8 structure (stats-LDS table + register product-history, 2-step fused body,
// coalesced stores) with ONE delta: slot1 is branch-free. Lanes past the
// triangle (tid >= 268) compute duplicate pairs p = tid+244 in [512,755]:
// distinct addresses, bit-identical values (same LDS data, same ops) -> no
// exec-mask traffic in phase 2, slot1 LDS reads overlap slot0's lgkm wait.
__global__ __launch_bounds__(NT, 8) void ts_corr_r12(const float* __restrict__ in,
                                                     float* __restrict__ out) {
    const int blk = blockIdx.x;
    const int b   = blk >> 3;              // / NCHUNK
    const int c   = blk & (NCHUNK - 1);
    const int s0  = (c == NCHUNK - 1) ? (NS - SC) : c * SC;   // 439 tail; overlap rows identical
    const int tid = threadIdx.x;

    __shared__ float  xs[SC + WW][FF];   // 74 rows (73 used + pad) = 11840 B
    __shared__ float2 st[SC][FF];        // (u*sqrt(0.1), m*u) = 20480 B

    // ---- phase 0: stage 73-row slab, float4 (730 quads) ----
    const float4* src4 = (const float4*)(in + ((size_t)b * TT + s0) * FF);
    float4* xs4 = (float4*)&xs[0][0];
    {
        xs4[tid] = src4[tid];                       // 0..511
        const int i2 = tid + NT;
        if (i2 < ROWS * FF / 4) xs4[i2] = src4[i2]; // 512..729
    }
    __syncthreads();

    // ---- phase 1: stats for all 64 steps (640 feature-quads) ----
    #pragma unroll
    for (int k = 0; k < 2; ++k) {
        const int qd = tid + k * NT;
        if (qd < SC * FF / 4) {
            const int t  = qd / 10;
            const int f0 = (qd - t * 10) * 4;
            float sx0=0,sx1=0,sx2=0,sx3=0, sq0=0,sq1=0,sq2=0,sq3=0;
            #pragma unroll
            for (int w = 0; w < WW; ++w) {
                const float4 x = *(const float4*)&xs[t + w][f0];
                sx0 += x.x; sx1 += x.y; sx2 += x.z; sx3 += x.w;
                sq0 += x.x*x.x; sq1 += x.y*x.y; sq2 += x.z*x.z; sq3 += x.w*x.w;
            }
            const float m0 = sx0*0.1f, m1 = sx1*0.1f, m2 = sx2*0.1f, m3 = sx3*0.1f;
            const float u0 = 1.f/(sqrtf(fmaxf(sq0*0.1f - m0*m0, 0.f)) + EPSC);
            const float u1 = 1.f/(sqrtf(fmaxf(sq1*0.1f - m1*m1, 0.f)) + EPSC);
            const float u2 = 1.f/(sqrtf(fmaxf(sq2*0.1f - m2*m2, 0.f)) + EPSC);
            const float u3 = 1.f/(sqrtf(fmaxf(sq3*0.1f - m3*m3, 0.f)) + EPSC);
            *(float4*)&st[t][f0]     = make_float4(u0*C01, m0*u0, u1*C01, m1*u1);
            *(float4*)&st[t][f0 + 2] = make_float4(u2*C01, m2*u2, u3*C01, m3*u3);
        }
    }

    // ---- pair setup + initial window (xs ready since phase-0 barrier) ----
    // slot0: p = tid; slot1: p = tid+512, or dup pair tid+244 if past triangle
    int pi[2], pj[2], poff[2];
    float sxy[2], ph[2][WW];
    #pragma unroll
    for (int k = 0; k < 2; ++k) {
        int p = tid + k * NT;
        if (p >= NP) p = p - NP + 512;     // tid+244: dup pairs [512,755], distinct addrs
        poff[k] = p;
        int i = (int)((79.0f - sqrtf((float)(6241 - 8 * p))) * 0.5f);
        while (i > 0 && i * (79 - i) / 2 > p) --i;
        while ((i + 1) * (79 - (i + 1)) / 2 <= p) ++i;
        pi[k] = i;
        pj[k] = p - i * (79 - i) / 2 + i + 1;
        float s = 0.f;
        #pragma unroll
        for (int w = 0; w < WW; ++w) {
            const float pr = xs[w][pi[k]] * xs[w][pj[k]];
            ph[k][w] = pr;
            s += pr;
        }
        sxy[k] = s;
    }
    __syncthreads();   // st ready; no barriers after this

    float* dstB = out + (size_t)(b * NS + s0) * NP;

// Two steps (TA, TA+1); U, DO2 literals. Fully branch-free.
#define SLOT(K) do {                                                            \
    const int _ii = pi[K], _jj = pj[K];                                         \
    const float  _xiA = xs[_tA + WW][_ii], _xiB = xs[_tA + WW + 1][_ii];        \
    const float  _xjA = xs[_tA + WW][_jj], _xjB = xs[_tA + WW + 1][_jj];        \
    const float2 _siA = st[_tA][_ii],      _siB = st[_tA + 1][_ii];             \
    const float2 _sjA = st[_tA][_jj],      _sjB = st[_tA + 1][_jj];             \
    _dA[poff[K]] = sxy[K] * _siA.x * _sjA.x - _siA.y * _sjA.y;                  \
    const float _pn = _xiA * _xjA;                                              \
    sxy[K] += _pn - ph[K][U]; ph[K][U] = _pn;                                   \
    _dB[poff[K]] = sxy[K] * _siB.x * _sjB.x - _siB.y * _sjB.y;                  \
    if (DO2) {                                                                  \
        const float _p2 = _xiB * _xjB;                                          \
        sxy[K] += _p2 - ph[K][(U) + 1]; ph[K][(U) + 1] = _p2;                   \
    }                                                                           \
} while (0)

#define STEP2(UU, TA, DD) do {                                                  \
    const int _tA = (TA);                                                       \
    const int U = (UU);                                                         \
    const bool DO2 = (DD);                                                      \
    float* _dA = dstB + (size_t)_tA * NP;                                       \
    float* _dB = _dA + NP;                                                      \
    SLOT(0);                                                                    \
    SLOT(1);                                                                    \
} while (0)

    // ---- phase 2: t = 0..59 regular, epilogue t = 60..63 ----
    for (int t0 = 0; t0 < 60; t0 += WW) {
        STEP2(0, t0,     true);
        STEP2(2, t0 + 2, true);
        STEP2(4, t0 + 4, true);
        STEP2(6, t0 + 6, true);
        STEP2(8, t0 + 8, true);
    }
    STEP2(0, 60, true);
    STEP2(2, 62, false);
#undef STEP2
#undef SLOT
}

extern "C" void kernel_launch(void* const* d_in, const int* in_sizes, int n_in,
                              void* d_out, int out_size, void* d_ws, size_t ws_size,
                              hipStream_t stream) {
    const float* in = (const float*)d_in[0];
    float* out = (float*)d_out;
    ts_corr_r12<<<BB * NCHUNK, NT, 0, stream>>>(in, out);
}

// Round 13
// 44.060 us; speedup vs baseline: 15.0236x; 1.2943x over previous
//
#include <hip/hip_runtime.h>
#include <hip/hip_fp16.h>

#define BB   128
#define TT   512
#define FF   40
#define WW   10
#define NS   503            // window starts (stride 1): T-W+1
#define NP   780            // F*(F-1)/2
#define SC   64             // steps per block (uniform; last chunk overlaps)
#define NCHUNK 8
#define ROWS (SC + WW - 1)  // 73 staged rows
#define NT   512            // threads per block (8 waves)
#define EPSC 1e-5f
#define C01  0.31622776601683794f   // sqrt(0.1)

// r8 structure verbatim (stats table + register product-history, 2-step fused
// body, wave-uniform slot1 skip, coalesced stores) with ONE delta: the stats
// table is packed __half2 (u*sqrt(0.1), m*u) -> stats LDS bytes per output
// halve (16B -> 8B). LDS/output: 24B -> 16B, under the ~31us HBM store floor.
__global__ __launch_bounds__(NT, 8) void ts_corr_r13(const float* __restrict__ in,
                                                     float* __restrict__ out) {
    const int blk = blockIdx.x;
    const int b   = blk >> 3;              // / NCHUNK
    const int c   = blk & (NCHUNK - 1);
    const int s0  = (c == NCHUNK - 1) ? (NS - SC) : c * SC;   // 439 tail; overlap rows identical
    const int tid = threadIdx.x;

    __shared__ float   xs[SC + WW][FF];  // 74 rows (73 used + pad) = 11840 B
    __shared__ __half2 st[SC][FF];       // packed (u*sqrt(0.1), m*u) = 10240 B

    // ---- phase 0: stage 73-row slab, float4 (730 quads) ----
    const float4* src4 = (const float4*)(in + ((size_t)b * TT + s0) * FF);
    float4* xs4 = (float4*)&xs[0][0];
    {
        xs4[tid] = src4[tid];                       // 0..511
        const int i2 = tid + NT;
        if (i2 < ROWS * FF / 4) xs4[i2] = src4[i2]; // 512..729
    }
    __syncthreads();

    // ---- phase 1: stats for all 64 steps (640 feature-quads), f16-packed ----
    #pragma unroll
    for (int k = 0; k < 2; ++k) {
        const int qd = tid + k * NT;
        if (qd < SC * FF / 4) {
            const int t  = qd / 10;
            const int f0 = (qd - t * 10) * 4;
            float sx0=0,sx1=0,sx2=0,sx3=0, sq0=0,sq1=0,sq2=0,sq3=0;
            #pragma unroll
            for (int w = 0; w < WW; ++w) {
                const float4 x = *(const float4*)&xs[t + w][f0];
                sx0 += x.x; sx1 += x.y; sx2 += x.z; sx3 += x.w;
                sq0 += x.x*x.x; sq1 += x.y*x.y; sq2 += x.z*x.z; sq3 += x.w*x.w;
            }
            const float m0 = sx0*0.1f, m1 = sx1*0.1f, m2 = sx2*0.1f, m3 = sx3*0.1f;
            const float u0 = 1.f/(sqrtf(fmaxf(sq0*0.1f - m0*m0, 0.f)) + EPSC);
            const float u1 = 1.f/(sqrtf(fmaxf(sq1*0.1f - m1*m1, 0.f)) + EPSC);
            const float u2 = 1.f/(sqrtf(fmaxf(sq2*0.1f - m2*m2, 0.f)) + EPSC);
            const float u3 = 1.f/(sqrtf(fmaxf(sq3*0.1f - m3*m3, 0.f)) + EPSC);
            st[t][f0]     = __floats2half2_rn(u0*C01, m0*u0);
            st[t][f0 + 1] = __floats2half2_rn(u1*C01, m1*u1);
            st[t][f0 + 2] = __floats2half2_rn(u2*C01, m2*u2);
            st[t][f0 + 3] = __floats2half2_rn(u3*C01, m3*u3);
        }
    }

    // ---- pair setup + initial window (xs ready since phase-0 barrier) ----
    int pi[2], pj[2];
    float sxy[2], ph[2][WW];
    #pragma unroll
    for (int k = 0; k < 2; ++k) {
        const int p = tid + k * NT;
        const int pp = (p < NP) ? p : 0;
        int i = (int)((79.0f - sqrtf((float)(6241 - 8 * pp))) * 0.5f);
        while (i > 0 && i * (79 - i) / 2 > pp) --i;
        while ((i + 1) * (79 - (i + 1)) / 2 <= pp) ++i;
        pi[k] = i;
        pj[k] = pp - i * (79 - i) / 2 + i + 1;
        float s = 0.f;
        #pragma unroll
        for (int w = 0; w < WW; ++w) {
            const float pr = xs[w][pi[k]] * xs[w][pj[k]];
            ph[k][w] = pr;
            s += pr;
        }
        sxy[k] = s;
    }
    __syncthreads();   // st ready; no barriers after this

    const bool act1 = (tid < NP - NT);   // slot-1 live lanes (tid < 268); wave-uniform skip for waves 5..7
    float* dst0 = out + (size_t)(b * NS + s0) * NP + tid;

// Two steps (TA, TA+1); U, DO2 are literals.
#define SLOT(K, OFF) do {                                                       \
    const int _ii = pi[K], _jj = pj[K];                                         \
    const float  _xiA = xs[_tA + WW][_ii], _xiB = xs[_tA + WW + 1][_ii];        \
    const float  _xjA = xs[_tA + WW][_jj], _xjB = xs[_tA + WW + 1][_jj];        \
    const float2 _siA = __half22float2(st[_tA][_ii]);                           \
    const float2 _siB = __half22float2(st[_tA + 1][_ii]);                       \
    const float2 _sjA = __half22float2(st[_tA][_jj]);                           \
    const float2 _sjB = __half22float2(st[_tA + 1][_jj]);                       \
    _dA[OFF] = sxy[K] * _siA.x * _sjA.x - _siA.y * _sjA.y;                      \
    const float _pn = _xiA * _xjA;                                              \
    sxy[K] += _pn - ph[K][U]; ph[K][U] = _pn;                                   \
    _dB[OFF] = sxy[K] * _siB.x * _sjB.x - _siB.y * _sjB.y;                      \
    if (DO2) {                                                                  \
        const float _p2 = _xiB * _xjB;                                          \
        sxy[K] += _p2 - ph[K][(U) + 1]; ph[K][(U) + 1] = _p2;                   \
    }                                                                           \
} while (0)

#define STEP2(UU, TA, DD) do {                                                  \
    const int _tA = (TA);                                                       \
    const int U = (UU);                                                         \
    const bool DO2 = (DD);                                                      \
    float* _dA = dst0 + (size_t)_tA * NP;                                       \
    float* _dB = _dA + NP;                                                      \
    SLOT(0, 0);                                                                 \
    if (act1) SLOT(1, NT);                                                      \
} while (0)

    // ---- phase 2: t = 0..59 regular, epilogue t = 60..63 ----
    for (int t0 = 0; t0 < 60; t0 += WW) {
        STEP2(0, t0,     true);
        STEP2(2, t0 + 2, true);
        STEP2(4, t0 + 4, true);
        STEP2(6, t0 + 6, true);
        STEP2(8, t0 + 8, true);
    }
    STEP2(0, 60, true);
    STEP2(2, 62, false);   // B-update reads pad row 73; discarded (DO2=false)
#undef STEP2
#undef SLOT
}

extern "C" void kernel_launch(void* const* d_in, const int* in_sizes, int n_in,
                              void* d_out, int out_size, void* d_ws, size_t ws_size,
                              hipStream_t stream) {
    const float* in = (const float*)d_in[0];
    float* out = (float*)d_out;
    ts_corr_r13<<<BB * NCHUNK, NT, 0, stream>>>(in, out);
}

// Round 14
// 44.018 us; speedup vs baseline: 15.0379x; 1.0010x over previous
//
#include <hip/hip_runtime.h>
#include <hip/hip_fp16.h>

#define BB   128
#define TT   512
#define FF   40
#define WW   10
#define NS   503            // window starts (stride 1): T-W+1
#define NP   780            // F*(F-1)/2
#define SC   64             // steps per block (uniform; last chunk overlaps)
#define NCHUNK 8
#define NT   512            // threads per block (8 waves)
#define XCOL 76             // xs_t cols (mult of 4): data at 2..74 (73 rows), 75 pad
#define SCOL 68             // st_t cols (mult of 4): data at 0..63
#define EPSC 1e-5f
#define C01  0.31622776601683794f   // sqrt(0.1)

// T-MAJOR LDS + 4-step fused body: per slot per 4 outputs exactly 4 ds_read_b128
// (x_i, x_j at t+10..t+13; packed f16 stats at t..t+3) -> 1 LDS instr/output
// (r13: 2), moving LDS from issue-limited to BW-limited. i-reads broadcast
// (wave shares row i); j-reads stride-76/68-dword -> full bank coverage per
// 8 lanes. No min-waves launch bound (r7/r10 spill lesson). Static history
// indices: U-pattern period lcm(4,10)=20 -> 5 STEP4 per 20 steps.
__global__ __launch_bounds__(NT) void ts_corr_r14(const float* __restrict__ in,
                                                  float* __restrict__ out) {
    const int blk = blockIdx.x;
    const int b   = blk >> 3;              // / NCHUNK
    const int c   = blk & (NCHUNK - 1);
    const int s0  = (c == NCHUNK - 1) ? (NS - SC) : c * SC;   // 439 tail; overlap rows identical
    const int tid = threadIdx.x;

    __shared__ __align__(16) float   xs_t[FF][XCOL];   // 12160 B
    __shared__ __align__(16) __half2 st_t[FF][SCOL];   // 10880 B  (u*sqrt(0.1), m*u)

    // ---- phase 0: stage transposed (coalesced float4 global reads) ----
    const float4* src4 = (const float4*)(in + ((size_t)b * TT + s0) * FF);
    #pragma unroll
    for (int k = 0; k < 2; ++k) {
        const int q = tid + k * NT;
        if (q < (SC + WW - 1) * FF / 4) {   // 730 quads
            const int r  = q / 10;
            const int f0 = (q - r * 10) * 4;
            const float4 v = src4[q];
            xs_t[f0    ][2 + r] = v.x;
            xs_t[f0 + 1][2 + r] = v.y;
            xs_t[f0 + 2][2 + r] = v.z;
            xs_t[f0 + 3][2 + r] = v.w;
        }
    }
    __syncthreads();

    // ---- phase 1 (tid<320): rolling stats, f = tid>>3, 8 t's each ----
    if (tid < 320) {
        const int f  = tid >> 3;
        const int t0 = (tid & 7) * 8;
        float sx = 0.f, sq = 0.f;
        #pragma unroll
        for (int w = 0; w < WW; ++w) {
            const float x = xs_t[f][2 + t0 + w];
            sx += x; sq += x * x;
        }
        #pragma unroll
        for (int u = 0; u < 8; ++u) {
            const int t = t0 + u;
            const float m  = sx * 0.1f;
            const float vv = fmaxf(sq * 0.1f - m * m, 0.f);
            const float iu = 1.f / (sqrtf(vv) + EPSC);
            st_t[f][t] = __floats2half2_rn(iu * C01, m * iu);
            if (u < 7) {
                const float xo = xs_t[f][2 + t], xn = xs_t[f][2 + t + WW];
                sx += xn - xo; sq += xn * xn - xo * xo;
            }
        }
    }

    // ---- pair setup + initial window (all threads; xs ready) ----
    int pi[2], pj[2];
    float sxy[2], ph[2][WW];
    #pragma unroll
    for (int k = 0; k < 2; ++k) {
        const int p0 = tid + k * NT;
        const int pp = (p0 < NP) ? p0 : 0;
        int i = (int)((79.0f - sqrtf((float)(6241 - 8 * pp))) * 0.5f);
        while (i > 0 && i * (79 - i) / 2 > pp) --i;
        while ((i + 1) * (79 - (i + 1)) / 2 <= pp) ++i;
        pi[k] = i;
        pj[k] = pp - i * (79 - i) / 2 + i + 1;
        float s = 0.f;
        #pragma unroll
        for (int w2 = 0; w2 < WW; w2 += 2) {
            const float2 a  = *(const float2*)&xs_t[pi[k]][2 + w2];
            const float2 bb = *(const float2*)&xs_t[pj[k]][2 + w2];
            const float q0 = a.x * bb.x, q1 = a.y * bb.y;
            ph[k][w2] = q0; ph[k][w2 + 1] = q1;
            s += q0 + q1;
        }
        sxy[k] = s;
    }
    __syncthreads();   // st ready; no barriers after this

    const bool act1 = (tid < NP - NT);   // slot-1 live (tid<268); wave-uniform skip waves 5..7
    float* dst0 = out + (size_t)(b * NS + s0) * NP + tid;

#define H2F2(U) __half22float2(__builtin_bit_cast(__half2, (U)))

// 4 steps (t.._tA+3); U0..U3 literals (static ph indices); DOLAST literal.
#define SLOT4(K, OFF, U0, U1, U2, U3, DOLAST) do {                              \
    const float4 _xi = *(const float4*)&xs_t[pi[K]][2 + _tA + WW];              \
    const float4 _xj = *(const float4*)&xs_t[pj[K]][2 + _tA + WW];              \
    const uint4  _si = *(const uint4*)&st_t[pi[K]][_tA];                        \
    const uint4  _sj = *(const uint4*)&st_t[pj[K]][_tA];                        \
    float2 _a, _b2; float _pn;                                                  \
    _a = H2F2(_si.x); _b2 = H2F2(_sj.x);                                        \
    _d0[OFF] = sxy[K] * _a.x * _b2.x - _a.y * _b2.y;                            \
    _pn = _xi.x * _xj.x; sxy[K] += _pn - ph[K][U0]; ph[K][U0] = _pn;            \
    _a = H2F2(_si.y); _b2 = H2F2(_sj.y);                                        \
    _d1[OFF] = sxy[K] * _a.x * _b2.x - _a.y * _b2.y;                            \
    _pn = _xi.y * _xj.y; sxy[K] += _pn - ph[K][U1]; ph[K][U1] = _pn;            \
    _a = H2F2(_si.z); _b2 = H2F2(_sj.z);                                        \
    _d2[OFF] = sxy[K] * _a.x * _b2.x - _a.y * _b2.y;                            \
    _pn = _xi.z * _xj.z; sxy[K] += _pn - ph[K][U2]; ph[K][U2] = _pn;            \
    _a = H2F2(_si.w); _b2 = H2F2(_sj.w);                                        \
    _d3[OFF] = sxy[K] * _a.x * _b2.x - _a.y * _b2.y;                            \
    if (DOLAST) {                                                               \
        _pn = _xi.w * _xj.w; sxy[K] += _pn - ph[K][U3]; ph[K][U3] = _pn;        \
    }                                                                           \
} while (0)

#define STEP4(U0, U1, U2, U3, TA, DOLAST) do {                                  \
    const int _tA = (TA);                                                       \
    float* _d0 = dst0 + (size_t)_tA * NP;                                       \
    float* _d1 = _d0 + NP;                                                      \
    float* _d2 = _d0 + 2 * NP;                                                  \
    float* _d3 = _d0 + 3 * NP;                                                  \
    SLOT4(0, 0, U0, U1, U2, U3, DOLAST);                                        \
    if (act1) SLOT4(1, NT, U0, U1, U2, U3, DOLAST);                             \
} while (0)

    // ---- phase 2: history pattern period 20 (lcm(4,10)); 3 iters + epilogue ----
    for (int t0 = 0; t0 < 60; t0 += 20) {
        STEP4(0, 1, 2, 3, t0,      true);
        STEP4(4, 5, 6, 7, t0 + 4,  true);
        STEP4(8, 9, 0, 1, t0 + 8,  true);
        STEP4(2, 3, 4, 5, t0 + 12, true);
        STEP4(6, 7, 8, 9, t0 + 16, true);
    }
    STEP4(0, 1, 2, 3, 60, false);   // xi.w/xj.w read pad col 75; dead (DOLAST=false)
#undef STEP4
#undef SLOT4
#undef H2F2
}

extern "C" void kernel_launch(void* const* d_in, const int* in_sizes, int n_in,
                              void* d_out, int out_size, void* d_ws, size_t ws_size,
                              hipStream_t stream) {
    const float* in = (const float*)d_in[0];
    float* out = (float*)d_out;
    ts_corr_r14<<<BB * NCHUNK, NT, 0, stream>>>(in, out);
}